// Round 23
// baseline (865.326 us; speedup 1.0000x reference)
//
#include <hip/hip_runtime.h>

// LSTM B=512,T=512,D=128,H=64,O=1. Gate order i,f,g,o.
// K1: pre = x@Wih0^T + bih0+bhh0 — fp16 MFMA (R15-proven, ~70us).
// K2: R13's all-LDS-weight recurrence (best: 547us, absmax 4.9e-4) with ONE
//   change: dot2f = 2x v_fma_mix_f32 inline asm.
//   R22 proved: (a) builtin fdot2 was NEVER used (fallback numerics differ from
//   real v_dot2_f32_f16); (b) real v_dot2 is low-precision on gfx950 (absmax
//   2.2e-2 — unusable); (c) the fallback costs ~2 inst/element (separate
//   v_cvt_f32_f16 + fmaf, ~256 inst/thread/step for 128 MACs — matches the
//   measured 261 VALU inst/wave/step). v_fma_mix_f32 does the fp16->fp32
//   convert INSIDE the fma (op_sel_hi:[1,1,0] = srcs 0,1 are f16, src2 f32;
//   op_sel picks lo/hi half) — bit-identical math, half the instructions.
// ws: 512*512*256*4 = 256 MiB fp32 pre (written by K1, read-only in K2).

#define TSTEPS 512

typedef _Float16 h2v __attribute__((ext_vector_type(2)));
typedef _Float16 half8 __attribute__((ext_vector_type(8)));
typedef __attribute__((ext_vector_type(4))) float facc;

__device__ __forceinline__ float sigf(float x){ return 1.0f/(1.0f+__expf(-x)); }
__device__ __forceinline__ float tanh_fast(float x){
  float ax=fabsf(x); float e=__expf(-2.0f*ax); float r=(1.0f-e)/(1.0f+e); return copysignf(r,x);
}
__device__ __forceinline__ unsigned packh(float a, float b){
  unsigned short la = __builtin_bit_cast(unsigned short, (_Float16)a);
  unsigned short lb = __builtin_bit_cast(unsigned short, (_Float16)b);
  return (unsigned)la | ((unsigned)lb << 16);
}
// 2 fp16 pairs -> fp32 acc via two v_fma_mix_f32 (exact cvt + fp32 fma:
// bit-identical to the old cvt+fmaf fallback, 1 inst/element instead of 2)
__device__ __forceinline__ float dot2f(unsigned wu, unsigned hu, float acc){
  asm("v_fma_mix_f32 %0, %1, %2, %0 op_sel_hi:[1,1,0]"
      : "+v"(acc) : "v"(wu), "v"(hu));
  asm("v_fma_mix_f32 %0, %1, %2, %0 op_sel:[1,1,0] op_sel_hi:[1,1,0]"
      : "+v"(acc) : "v"(wu), "v"(hu));
  return acc;
}
// a + dpp_quad_perm(b); 0xB1 = xor1 [1,0,3,2], 0x4E = xor2 [2,3,0,1]
template<int CTRL>
__device__ __forceinline__ float add_dpp(float a, float b){
  return a + __int_as_float(__builtin_amdgcn_update_dpp(
      0, __float_as_int(b), CTRL, 0xF, 0xF, true));
}

// ---------------- K1: input projection GEMM (fp16 MFMA, R15) ----------------
__global__ __launch_bounds__(256) void k_inproj(
    const float* __restrict__ x, const float* __restrict__ W,
    const float* __restrict__ bih, const float* __restrict__ bhh,
    float* __restrict__ pre)
{
    __shared__ __align__(16) _Float16 Ah[64][136];
    __shared__ __align__(16) _Float16 Bh[256][136];
    const int tid = threadIdx.x;
    const long row0 = (long)blockIdx.x * 64;

    {
        const int r = tid >> 2, c0 = (tid & 3) * 32;
        const float4* src = (const float4*)(x + (row0 + r) * 128 + c0);
#pragma unroll
        for (int i = 0; i < 4; ++i) {
            float4 v0 = src[2 * i], v1 = src[2 * i + 1];
            half8 hv = { (_Float16)v0.x, (_Float16)v0.y, (_Float16)v0.z, (_Float16)v0.w,
                         (_Float16)v1.x, (_Float16)v1.y, (_Float16)v1.z, (_Float16)v1.w };
            *(half8*)&Ah[r][c0 + 8 * i] = hv;
        }
    }
    {
        const float4* src = (const float4*)(W + tid * 128);
#pragma unroll
        for (int i = 0; i < 16; ++i) {
            float4 v0 = src[2 * i], v1 = src[2 * i + 1];
            half8 hv = { (_Float16)v0.x, (_Float16)v0.y, (_Float16)v0.z, (_Float16)v0.w,
                         (_Float16)v1.x, (_Float16)v1.y, (_Float16)v1.z, (_Float16)v1.w };
            *(half8*)&Bh[tid][8 * i] = hv;
        }
    }
    __syncthreads();

    const int w  = tid >> 6;
    const int l  = tid & 63;
    const int lm = l & 15;
    const int lk = l >> 4;
    const int n0 = w * 64;

    facc acc[4][4];
#pragma unroll
    for (int mi = 0; mi < 4; ++mi)
#pragma unroll
        for (int ni = 0; ni < 4; ++ni) acc[mi][ni] = (facc){0.f, 0.f, 0.f, 0.f};

#pragma unroll
    for (int ks = 0; ks < 4; ++ks) {
        const int kk = ks * 32 + lk * 8;
        half8 Af[4], Bf[4];
#pragma unroll
        for (int mi = 0; mi < 4; ++mi) Af[mi] = *(const half8*)&Ah[mi * 16 + lm][kk];
#pragma unroll
        for (int ni = 0; ni < 4; ++ni) Bf[ni] = *(const half8*)&Bh[n0 + ni * 16 + lm][kk];
#pragma unroll
        for (int mi = 0; mi < 4; ++mi)
#pragma unroll
            for (int ni = 0; ni < 4; ++ni)
                acc[mi][ni] = __builtin_amdgcn_mfma_f32_16x16x32_f16(
                    Af[mi], Bf[ni], acc[mi][ni], 0, 0, 0);
    }

    float bs[4];
#pragma unroll
    for (int ni = 0; ni < 4; ++ni) {
        const int n = n0 + ni * 16 + lm;
        bs[ni] = bih[n] + bhh[n];
    }
#pragma unroll
    for (int mi = 0; mi < 4; ++mi) {
#pragma unroll
        for (int ni = 0; ni < 4; ++ni) {
            const int n = n0 + ni * 16 + lm;
#pragma unroll
            for (int r = 0; r < 4; ++r) {
                const long row = row0 + mi * 16 + lk * 4 + r;
                pre[row * 256 + n] = acc[mi][ni][r] + bs[ni];
            }
        }
    }
}

// ---------------- K2: fused 2-layer recurrence + head (R13 verbatim) --------
__global__ __attribute__((amdgpu_flat_work_group_size(768, 768)))
void k_fused(
    const float* __restrict__ Whh0, const float* __restrict__ Wih1,
    const float* __restrict__ Whh1,
    const float* __restrict__ bih1, const float* __restrict__ bhh1,
    const float* __restrict__ Wfc,  const float* __restrict__ bfc,
    const float* __restrict__ pre,  float* __restrict__ out)
{
    const int tid = threadIdx.x;
    const int ll  = tid & 3;          // lane-in-quad = k-slice index
    const int q   = tid >> 2;         // quad 0..191: rows 4q..4q+3 (global 0..767)
    const int m   = q >> 6;           // matrix: 0=Whh0, 1=Wih1, 2=Whh1
    const int lay = (m == 2) ? 1 : 0; // h layer my matrix consumes
    const int cA  = (ll >> 1) & 1;    // surviving batch slot
    const int cB  = cA ^ 1;

    __shared__ __align__(16) uint4 wl4[8][768];     // 96KB per-thread weight streams
    __shared__ unsigned hp[2][2][2][32];            // 1KB [par][batch][layer][32u]=64 fp16
    __shared__ float zl[2][768];                    // 6KB dot results [batch][row]

    // ---- one-time: pack my 4 rows (permuted) x k-slice into my stream ----
    {
        const float* Wm = (m == 0) ? Whh0 : ((m == 1) ? Wih1 : Whh1);
        const int rofs[4] = { (ll & 1), 2 + (ll & 1), 1 - (ll & 1), 3 - (ll & 1) };
#pragma unroll
        for (int rs = 0; rs < 4; ++rs) {
            const int rr = (4 * q + rofs[rs]) & 255;       // row within matrix
            const float4* src = (const float4*)(Wm + rr * 64 + 16 * ll);
            float4 f0 = src[0], f1 = src[1], f2 = src[2], f3 = src[3];
            uint4 u0, u1;
            u0.x = packh(f0.x, f0.y); u0.y = packh(f0.z, f0.w);
            u0.z = packh(f1.x, f1.y); u0.w = packh(f1.z, f1.w);
            u1.x = packh(f2.x, f2.y); u1.y = packh(f2.z, f2.w);
            u1.z = packh(f3.x, f3.y); u1.w = packh(f3.z, f3.w);
            wl4[rs * 2 + 0][tid] = u0;
            wl4[rs * 2 + 1][tid] = u1;
        }
    }
    if (tid < 256) ((unsigned*)hp)[tid] = 0;   // h_{-1}=0 both parities

    // ---- updater role (tid<256): c=batch, l=layer, j=unit ----
    const int c_u = tid >> 7;
    const int l_u = (tid >> 6) & 1;
    const int j_u = tid & 63;
    const long bb = (long)blockIdx.x * 2;
    float bias1v[4] = {0, 0, 0, 0};
    float pc[4] = {0, 0, 0, 0};
    if (tid < 256) {
        if (l_u == 1) {
#pragma unroll
            for (int g = 0; g < 4; ++g) bias1v[g] = bih1[g * 64 + j_u] + bhh1[g * 64 + j_u];
        } else {
            const float* pb = pre + (bb + c_u) * TSTEPS * 256;
#pragma unroll
            for (int g = 0; g < 4; ++g) pc[g] = pb[g * 64 + j_u];   // t=0
        }
    }
    float cst = 0.0f, h1last = 0.0f;
    int p = 0;
    __syncthreads();

#pragma unroll 1
    for (int n = 0; n <= TSTEPS; ++n) {
        // prefetch pre for t=n+1 (layer-0 updaters)
        float pn[4] = {0, 0, 0, 0};
        if (tid < 256 && l_u == 0) {
            const int tn = (n + 1 < TSTEPS) ? n + 1 : 0;
            const float* pb = pre + ((bb + c_u) * TSTEPS + tn) * 256;
#pragma unroll
            for (int g = 0; g < 4; ++g) pn[g] = pb[g * 64 + j_u];
        }

        // ---- h slices (my k-slice, both batch slots): 4 b128, broadcast ----
        uint4 hA0 = *(const uint4*)&hp[p][cA][lay][ll * 8];
        uint4 hA1 = *(const uint4*)&hp[p][cA][lay][ll * 8 + 4];
        uint4 hB0 = *(const uint4*)&hp[p][cB][lay][ll * 8];
        uint4 hB1 = *(const uint4*)&hp[p][cB][lay][ll * 8 + 4];

        // ---- partial dots: 4 row-slots x 2 batch-slots, k=16 each ----
        float pA[4], pB[4];
#pragma unroll
        for (int rs = 0; rs < 4; ++rs) {
            uint4 w0 = wl4[rs * 2 + 0][tid];
            uint4 w1 = wl4[rs * 2 + 1][tid];
            float a = 0.0f, bA = 0.0f;
            a  = dot2f(w0.x, hA0.x, a);  a  = dot2f(w0.y, hA0.y, a);
            a  = dot2f(w0.z, hA0.z, a);  a  = dot2f(w0.w, hA0.w, a);
            a  = dot2f(w1.x, hA1.x, a);  a  = dot2f(w1.y, hA1.y, a);
            a  = dot2f(w1.z, hA1.z, a);  a  = dot2f(w1.w, hA1.w, a);
            bA = dot2f(w0.x, hB0.x, bA); bA = dot2f(w0.y, hB0.y, bA);
            bA = dot2f(w0.z, hB0.z, bA); bA = dot2f(w0.w, hB0.w, bA);
            bA = dot2f(w1.x, hB1.x, bA); bA = dot2f(w1.y, hB1.y, bA);
            bA = dot2f(w1.z, hB1.z, bA); bA = dot2f(w1.w, hB1.w, bA);
            pA[rs] = a; pB[rs] = bA;
        }

        // ---- select-free merges ----
        float q0A = add_dpp<0xB1>(pA[0], pA[2]);
        float q1A = add_dpp<0xB1>(pA[1], pA[3]);
        float q0B = add_dpp<0xB1>(pB[0], pB[2]);
        float q1B = add_dpp<0xB1>(pB[1], pB[3]);
        float r0 = add_dpp<0x4E>(q0A, q0B);
        float r1 = add_dpp<0x4E>(q1A, q1B);

        const int R0 = 4 * q + (ll & 1);
        zl[cA][R0]     = r0;
        zl[cA][R0 + 2] = r1;
        __syncthreads();   // zl ready

        // ---- cell updates ----
        if (tid < 256) {
            const bool valid = (l_u == 0) ? (n < TSTEPS) : (n >= 1);
            if (valid) {
                float z[4];
                if (l_u == 0) {
#pragma unroll
                    for (int g = 0; g < 4; ++g) z[g] = pc[g] + zl[c_u][g * 64 + j_u];
                } else {
#pragma unroll
                    for (int g = 0; g < 4; ++g)
                        z[g] = bias1v[g] + zl[c_u][256 + g * 64 + j_u] + zl[c_u][512 + g * 64 + j_u];
                }
                float i_ = sigf(z[0]), f_ = sigf(z[1]), g_ = tanh_fast(z[2]), o_ = sigf(z[3]);
                cst = fmaf(f_, cst, i_ * g_);
                float h = o_ * tanh_fast(cst);
                if (l_u) h1last = h;
                ((unsigned short*)&hp[p ^ 1][c_u][l_u][0])[j_u] =
                    __builtin_bit_cast(unsigned short, (_Float16)h);
            }
        }
        __syncthreads();   // new h visible
        p ^= 1;
        if (tid < 256 && l_u == 0) {
            pc[0] = pn[0]; pc[1] = pn[1]; pc[2] = pn[2]; pc[3] = pn[3];
        }
    }

    // ---- head: out[bb+c] = h1_{T-1} . Wfc + bfc ----
    if (tid < 256 && l_u == 1) {
        float v = h1last * Wfc[j_u];
#pragma unroll
        for (int off = 32; off > 0; off >>= 1) v += __shfl_down(v, off);
        if (j_u == 0) out[bb + c_u] = v + bfc[0];
    }
}

extern "C" void kernel_launch(void* const* d_in, const int* in_sizes, int n_in,
                              void* d_out, int out_size, void* d_ws, size_t ws_size,
                              hipStream_t stream)
{
    const float* x    = (const float*)d_in[0];
    const float* Wih0 = (const float*)d_in[1];
    const float* Whh0 = (const float*)d_in[2];
    const float* bih0 = (const float*)d_in[3];
    const float* bhh0 = (const float*)d_in[4];
    const float* Wih1 = (const float*)d_in[5];
    const float* Whh1 = (const float*)d_in[6];
    const float* bih1 = (const float*)d_in[7];
    const float* bhh1 = (const float*)d_in[8];
    const float* Wfc  = (const float*)d_in[9];
    const float* bfc  = (const float*)d_in[10];
    float* out = (float*)d_out;
    float* pre = (float*)d_ws;  // [B][T][256] fp32 = 256 MiB

    k_inproj<<<4096, 256, 0, stream>>>(x, Wih0, bih0, bhh0, pre);
    k_fused<<<256, 768, 0, stream>>>(Whh0, Wih1, Whh1, bih1, bhh1, Wfc, bfc, pre, out);
}